// Round 7
// baseline (176.718 us; speedup 1.0000x reference)
//
#include <hip/hip_runtime.h>
#include <hip/hip_bf16.h>
#include <stdint.h>

#define NN 51200
#define FF 400
#define HH 256
#define CC 2
#define EE 819200
#define GG 128
#define NEG 0.01f
#define NKT 13          // ceil(400/32) K-tiles of 32
#define PAD 64          // padded neighbor slots per node
#define NBK 200         // dst buckets = dst>>8
#define EB  4096        // edges per block in sort passes
#define NCH 8           // channel chunks (== #XCDs)
#define CCH 32          // channels per chunk -> chunk = 3.27 MB < 4 MB XCD L2

typedef unsigned int u32;
typedef unsigned short u16;
typedef __attribute__((ext_vector_type(8))) short s8;    // 8 bf16
typedef __attribute__((ext_vector_type(8))) u16 us8;     // 8 ushort indices
typedef __attribute__((ext_vector_type(4))) u32 u32x4;   // 16B, builtin-friendly
typedef __attribute__((ext_vector_type(4))) float f4;    // MFMA acc

__device__ __forceinline__ short f2bf(float f) {
    __hip_bfloat16 b = __float2bfloat16(f);
    return *reinterpret_cast<short*>(&b);
}
__device__ __forceinline__ float bflo(u32 x) { return __uint_as_float(x << 16); }
__device__ __forceinline__ float bfhi(u32 x) { return __uint_as_float(x & 0xffff0000u); }

// Order-preserving float<->uint encoding for atomicMax on floats.
__device__ __forceinline__ u32 encf(float f) {
    u32 u = __float_as_uint(f);
    return (u & 0x80000000u) ? ~u : (u | 0x80000000u);
}
__device__ __forceinline__ float decf(u32 e) {
    return (e & 0x80000000u) ? __uint_as_float(e & 0x7fffffffu)
                             : __uint_as_float(~e);
}

// ---- pack W[400][256] f32 -> wp[kt][nt][lane][8] bf16 fragment layout ----
__global__ void k_pack_w(const float* __restrict__ W, short* __restrict__ wp) {
    int t = blockIdx.x * 256 + threadIdx.x;        // (kt*16+nt)*64+l
    if (t >= NKT * 16 * 64) return;
    int l = t & 63;
    int k0 = (t >> 10) * 32 + ((l >> 4) * 8);
    int col = ((t >> 6) & 15) * 16 + (l & 15);
    s8 v;
    #pragma unroll
    for (int j = 0; j < 8; ++j) {
        int k = k0 + j;
        v[j] = f2bf((k < FF) ? W[(size_t)k * HH + col] : 0.f);
    }
    *(s8*)(wp + (size_t)t * 8) = v;
}

// ==== bucketed counting-sort CSR build ====

__global__ __launch_bounds__(256) void k_hist2(const int* __restrict__ col,
                                               int* __restrict__ bcnt) {
    __shared__ int sh[NBK];
    const int t = threadIdx.x;
    if (t < NBK) sh[t] = 0;
    __syncthreads();
    const int base = blockIdx.x * EB;
    for (int i = t; i < EB; i += 256)
        atomicAdd(&sh[col[base + i] >> 8], 1);
    __syncthreads();
    if (t < NBK && sh[t]) atomicAdd(&bcnt[t], sh[t]);
}

// scan of bucket counts; also zeroes the dummy rows of ht (8 chunks x 32 ch)
__global__ __launch_bounds__(256) void k_scan2(const int* __restrict__ bcnt,
                                               int* __restrict__ bbase,
                                               int* __restrict__ cursor,
                                               short* __restrict__ ht) {
    __shared__ int v[256];
    const int t = threadIdx.x;
    int mine = (t < NBK) ? bcnt[t] : 0;
    v[t] = mine;
    __syncthreads();
    for (int d = 1; d < 256; d <<= 1) {
        int x = (t >= d) ? v[t - d] : 0;
        __syncthreads();
        v[t] += x;
        __syncthreads();
    }
    if (t < NBK) { int e = v[t] - mine; bbase[t] = e; cursor[t] = e; }
    // dummy row NN of each chunk := 0
    ht[((size_t)(t >> 5) * (NN + 1) + NN) * CCH + (t & 31)] = 0;
}

__global__ __launch_bounds__(256) void k_place(const int* __restrict__ row,
                                               const int* __restrict__ col,
                                               int* __restrict__ cursor,
                                               u32* __restrict__ ebuf) {
    __shared__ int lcnt[NBK], lbase[NBK];
    const int t = threadIdx.x;
    if (t < NBK) lcnt[t] = 0;
    __syncthreads();
    const int base = blockIdx.x * EB;
    for (int i = t; i < EB; i += 256)
        atomicAdd(&lcnt[col[base + i] >> 8], 1);
    __syncthreads();
    if (t < NBK) {
        int c = lcnt[t];
        if (c) lbase[t] = atomicAdd(&cursor[t], c);
        lcnt[t] = 0;
    }
    __syncthreads();
    for (int i = t; i < EB; i += 256) {
        int d = col[base + i], s = row[base + i];
        int b = d >> 8;
        int lp = atomicAdd(&lcnt[b], 1);
        ebuf[lbase[b] + lp] = ((u32)s << 8) | (u32)(d & 255);
    }
}

// one block per bucket: ELL slice in LDS; pad slots = 0xFFFF (-> dummy row)
__global__ __launch_bounds__(256) void k_b2(const u32* __restrict__ ebuf,
                                            const int* __restrict__ bcnt,
                                            const int* __restrict__ bbase,
                                            int* __restrict__ cnt,
                                            u16* __restrict__ csr) {
    __shared__ u16 ell[256 * PAD];     // 32 KB
    __shared__ int h[256];
    const int t = threadIdx.x;
    const int b = blockIdx.x;
    int* elli = (int*)ell;
    for (int i = t; i < 256 * PAD / 2; i += 256) elli[i] = -1;
    h[t] = 0;
    __syncthreads();
    const int cb = bcnt[b], ba = bbase[b];
    for (int i = t; i < cb; i += 256) {
        u32 v = ebuf[ba + i];
        int dl = v & 255;
        int s = (int)(v >> 8);
        int p = atomicAdd(&h[dl], 1);
        if (p < PAD) ell[dl * PAD + p] = (u16)s;
    }
    __syncthreads();
    const int n0 = b << 8;
    cnt[n0 + t] = h[t];
    uint4* dst = (uint4*)(csr + (size_t)n0 * PAD);
    const uint4* src = (const uint4*)ell;
    for (int i = t; i < 256 * PAD * 2 / 16; i += 256) dst[i] = src[i];
}

// ---- MFMA GEMM: ht[chunk][N+1][32] = rsqrt(deg+1) * (x @ W), bf16 ----
__global__ __launch_bounds__(256) void k_mfma(
        const float* __restrict__ x, const short* __restrict__ wp,
        const int* __restrict__ cnt, short* __restrict__ ht)
{
    const int tid = threadIdx.x;
    const int l = tid & 63;
    const int w = tid >> 6;
    const int bm = blockIdx.x * 64;
    const int arow = bm + (l & 15);
    const int kl = (l >> 4) * 8;
    const s8* wb = (const s8*)wp;

    f4 acc[4][4] = {};
    for (int kt = 0; kt < NKT; ++kt) {
        const int k0 = kt * 32 + kl;
        s8 a[4];
        if (k0 < FF) {
            #pragma unroll
            for (int mi = 0; mi < 4; ++mi) {
                const float* p = x + (size_t)(arow + mi * 16) * FF + k0;
                float4 v0 = *(const float4*)p;
                float4 v1 = *(const float4*)(p + 4);
                a[mi][0] = f2bf(v0.x); a[mi][1] = f2bf(v0.y);
                a[mi][2] = f2bf(v0.z); a[mi][3] = f2bf(v0.w);
                a[mi][4] = f2bf(v1.x); a[mi][5] = f2bf(v1.y);
                a[mi][6] = f2bf(v1.z); a[mi][7] = f2bf(v1.w);
            }
        } else {
            #pragma unroll
            for (int mi = 0; mi < 4; ++mi)
                #pragma unroll
                for (int j = 0; j < 8; ++j) a[mi][j] = 0;
        }
        s8 b[4];
        #pragma unroll
        for (int ni = 0; ni < 4; ++ni)
            b[ni] = wb[(size_t)(kt * 16 + w * 4 + ni) * 64 + l];
        #pragma unroll
        for (int mi = 0; mi < 4; ++mi)
            #pragma unroll
            for (int ni = 0; ni < 4; ++ni)
                acc[mi][ni] = __builtin_amdgcn_mfma_f32_16x16x32_bf16(
                    a[mi], b[ni], acc[mi][ni], 0, 0, 0);
    }
    #pragma unroll
    for (int mi = 0; mi < 4; ++mi) {
        #pragma unroll
        for (int r = 0; r < 4; ++r) {
            const int rowg = bm + mi * 16 + (l >> 4) * 4 + r;
            const float dn = rsqrtf((float)(cnt[rowg] + 1));
            #pragma unroll
            for (int ni = 0; ni < 4; ++ni) {
                const int chunk = w * 2 + (ni >> 1);
                const int off = (ni & 1) * 16 + (l & 15);
                ht[((size_t)chunk * (NN + 1) + rowg) * CCH + off] =
                    f2bf(dn * acc[mi][ni][r]);
            }
        }
    }
}

// ---- gather + LeakyReLU + fused segment-max pool, XCD-pinned chunks ----
// chunk = blockIdx.x & 7 (round-robin XCD -> chunk k stays in XCD k's L2).
// Block: 64 nodes x 32 channels. 32 groups of 8 lanes; group = 1 node,
// lane = 4 channels (uint2 = 8 B); 2 node-iterations.
__global__ __launch_bounds__(256) void k_gather(
        const short* __restrict__ ht, const int* __restrict__ cnt,
        const u16* __restrict__ csr, const int* __restrict__ batch,
        const float* __restrict__ bg, u32* __restrict__ penc)
{
    __shared__ float4 sv[256];
    __shared__ int sb[256];
    const int t = threadIdx.x;
    const int g = t >> 3, li = t & 7;
    const int chunk = blockIdx.x & 7;
    const int tile = blockIdx.x >> 3;
    const short* hc = ht + (size_t)chunk * (NN + 1) * CCH;
    const int ch0 = chunk * CCH + li * 4;
    const float4 bias = *(const float4*)(bg + ch0);

    float m0 = 0.f, m1 = 0.f, m2 = 0.f, m3 = 0.f;
    int runb = -1;
    #pragma unroll
    for (int m = 0; m < 2; ++m) {
        const int n = tile * 64 + m * 32 + g;
        const int degt = __builtin_nontemporal_load(cnt + n);
        const int deg = (degt < PAD) ? degt : PAD;
        const float dn = rsqrtf((float)(degt + 1));
        uint2 s0 = *(const uint2*)(hc + (size_t)n * CCH + li * 4);
        float a0 = bflo(s0.x), a1 = bfhi(s0.x);
        float a2 = bflo(s0.y), a3 = bfhi(s0.y);
        int wmax = deg;                               // wave-uniform bound
        wmax = max(wmax, __shfl_xor(wmax, 8, 64));
        wmax = max(wmax, __shfl_xor(wmax, 16, 64));
        wmax = max(wmax, __shfl_xor(wmax, 32, 64));
        const u16* cp = csr + (size_t)n * PAD;
        for (int j0 = 0; j0 < wmax; j0 += 8) {
            u32x4 raw = __builtin_nontemporal_load((const u32x4*)(cp + j0));
            us8 iv;
            __builtin_memcpy(&iv, &raw, 16);
            #pragma unroll
            for (int k = 0; k < 8; ++k) {
                u32 ui = (u32)iv[k];
                ui = (ui < (u32)NN) ? ui : (u32)NN;   // pad -> dummy zero row
                uint2 v = *(const uint2*)(hc + (size_t)ui * CCH + li * 4);
                a0 += bflo(v.x); a1 += bfhi(v.x);
                a2 += bflo(v.y); a3 += bfhi(v.y);
            }
        }
        float v0 = dn * a0 + bias.x; v0 = (v0 >= 0.f) ? v0 : NEG * v0;
        float v1 = dn * a1 + bias.y; v1 = (v1 >= 0.f) ? v1 : NEG * v1;
        float v2 = dn * a2 + bias.z; v2 = (v2 >= 0.f) ? v2 : NEG * v2;
        float v3 = dn * a3 + bias.w; v3 = (v3 >= 0.f) ? v3 : NEG * v3;
        const int b = __builtin_nontemporal_load(batch + n);
        if (b != runb) {
            if (runb >= 0) {
                u32* p = penc + runb * HH + ch0;
                atomicMax(p + 0, encf(m0)); atomicMax(p + 1, encf(m1));
                atomicMax(p + 2, encf(m2)); atomicMax(p + 3, encf(m3));
            }
            runb = b; m0 = v0; m1 = v1; m2 = v2; m3 = v3;
        } else {
            m0 = fmaxf(m0, v0); m1 = fmaxf(m1, v1);
            m2 = fmaxf(m2, v2); m3 = fmaxf(m3, v3);
        }
    }
    sv[t] = make_float4(m0, m1, m2, m3);
    sb[t] = runb;
    __syncthreads();
    // threads 0..7 (one per li) merge runs across the 32 groups in node order
    if (t < 8) {
        int curb = sb[t];
        float4 cm = sv[t];
        for (int g2 = 1; g2 < 32; ++g2) {
            int bb = sb[t + 8 * g2];
            float4 vv = sv[t + 8 * g2];
            if (bb == curb) {
                cm.x = fmaxf(cm.x, vv.x); cm.y = fmaxf(cm.y, vv.y);
                cm.z = fmaxf(cm.z, vv.z); cm.w = fmaxf(cm.w, vv.w);
            } else {
                u32* p = penc + curb * HH + chunk * CCH + t * 4;
                atomicMax(p + 0, encf(cm.x)); atomicMax(p + 1, encf(cm.y));
                atomicMax(p + 2, encf(cm.z)); atomicMax(p + 3, encf(cm.w));
                curb = bb; cm = vv;
            }
        }
        u32* p = penc + curb * HH + chunk * CCH + t * 4;
        atomicMax(p + 0, encf(cm.x)); atomicMax(p + 1, encf(cm.y));
        atomicMax(p + 2, encf(cm.z)); atomicMax(p + 3, encf(cm.w));
    }
}

// ---- decode pool + write pool out + logits, one block per graph ----
__global__ __launch_bounds__(256) void k_out(
        const u32* __restrict__ penc, const float* __restrict__ Wl,
        const float* __restrict__ bl, float* __restrict__ out)
{
    __shared__ float r0[4], r1[4];
    const int g = blockIdx.x, t = threadIdx.x;
    float v = decf(penc[g * HH + t]);
    out[GG * CC + g * HH + t] = v;
    float s0 = v * Wl[t * CC + 0];
    float s1 = v * Wl[t * CC + 1];
    #pragma unroll
    for (int off = 32; off >= 1; off >>= 1) {
        s0 += __shfl_down(s0, off, 64);
        s1 += __shfl_down(s1, off, 64);
    }
    if ((t & 63) == 0) { r0[t >> 6] = s0; r1[t >> 6] = s1; }
    __syncthreads();
    if (t == 0) {
        out[g * CC + 0] = r0[0] + r0[1] + r0[2] + r0[3] + bl[0];
        out[g * CC + 1] = r1[0] + r1[1] + r1[2] + r1[3] + bl[1];
    }
}

extern "C" void kernel_launch(void* const* d_in, const int* in_sizes, int n_in,
                              void* d_out, int out_size, void* d_ws, size_t ws_size,
                              hipStream_t stream)
{
    const float* x    = (const float*)d_in[0];
    const int*   ei   = (const int*)d_in[1];
    const int*   batch= (const int*)d_in[2];
    const float* Wg   = (const float*)d_in[3];
    const float* bg   = (const float*)d_in[4];
    const float* Wl   = (const float*)d_in[5];
    const float* bl   = (const float*)d_in[6];
    float* out = (float*)d_out;
    const int* row = ei;        // sources
    const int* col = ei + EE;   // targets

    size_t o = 0;
    char* wsb = (char*)d_ws;
    auto take = [&](size_t b) { void* p = wsb + o; o += (b + 255) & ~(size_t)255; return p; };
    short* ht   = (short*)take((size_t)NCH * (NN + 1) * CCH * 2);     // 26.2 MB
    int*   bcnt = (int*)take((size_t)NBK * 4);
    u32*   penc = (u32*)take((size_t)GG * HH * 4);                    // adjacent
    int*   bbase= (int*)take((size_t)NBK * 4);
    int*   cursor=(int*)take((size_t)NBK * 4);
    int*   cnt  = (int*)take((size_t)NN * 4);
    u16*   csr  = (u16*)take((size_t)NN * PAD * 2);                   // 6.55 MB
    u32*   ebuf = (u32*)take((size_t)EE * 4);                         // 3.28 MB
    short* wp   = (short*)take((size_t)NKT * 16 * 64 * 8 * 2);        // 213 KB

    // one memset zeroes bcnt AND penc (adjacent, bcnt in a 256 B slot)
    hipMemsetAsync(bcnt, 0, 1024 + (size_t)GG * HH * 4, stream);

    k_hist2<<<NBK, 256, 0, stream>>>(col, bcnt);
    k_scan2<<<1, 256, 0, stream>>>(bcnt, bbase, cursor, ht);
    k_place<<<NBK, 256, 0, stream>>>(row, col, cursor, ebuf);
    k_b2<<<NBK, 256, 0, stream>>>(ebuf, bcnt, bbase, cnt, csr);
    k_pack_w<<<(NKT * 16 * 64 + 255) / 256, 256, 0, stream>>>(Wg, wp);
    k_mfma<<<NN / 64, 256, 0, stream>>>(x, wp, cnt, ht);
    k_gather<<<NN / 64 * NCH, 256, 0, stream>>>(ht, cnt, csr, batch, bg, penc);
    k_out<<<GG, 256, 0, stream>>>(penc, Wl, bl, out);
}

// Round 8
// 145.931 us; speedup vs baseline: 1.2110x; 1.2110x over previous
//
#include <hip/hip_runtime.h>
#include <hip/hip_bf16.h>
#include <stdint.h>

#define NN 51200
#define FF 400
#define HH 256
#define CC 2
#define EE 819200
#define GG 128
#define NEG 0.01f
#define NKT 13          // ceil(400/32) K-tiles of 32
#define PAD 64          // padded neighbor slots per node
#define NBK 200         // dst buckets = dst>>8
#define EB  4096        // edges per block in sort passes (EE/NBK)
#define SLOT 8192       // ebuf slots per bucket (pow2; mean fill 4096, sigma 64)

typedef unsigned int u32;
typedef unsigned short u16;
typedef __attribute__((ext_vector_type(8))) short s8;    // 8 bf16
typedef __attribute__((ext_vector_type(4))) u32 u32x4;   // 16B vector
typedef __attribute__((ext_vector_type(2))) float f2;    // packed f32 pair
typedef __attribute__((ext_vector_type(4))) float f4;    // MFMA acc

__device__ __forceinline__ short f2bf(float f) {
    __hip_bfloat16 b = __float2bfloat16(f);
    return *reinterpret_cast<short*>(&b);
}
__device__ __forceinline__ float bflo(u32 x) { return __uint_as_float(x << 16); }
__device__ __forceinline__ float bfhi(u32 x) { return __uint_as_float(x & 0xffff0000u); }

// Order-preserving float<->uint encoding for atomicMax on floats.
__device__ __forceinline__ u32 encf(float f) {
    u32 u = __float_as_uint(f);
    return (u & 0x80000000u) ? ~u : (u | 0x80000000u);
}
__device__ __forceinline__ float decf(u32 e) {
    return (e & 0x80000000u) ? __uint_as_float(e & 0x7fffffffu)
                             : __uint_as_float(~e);
}

// ---- pack W -> fragment layout; last block zeroes dummy row h[NN] ----
__global__ void k_pack_w(const float* __restrict__ W, short* __restrict__ wp,
                         short* __restrict__ h) {
    if (blockIdx.x == gridDim.x - 1) {
        if (threadIdx.x < 128)
            ((u32*)h)[(size_t)NN * 128 + threadIdx.x] = 0;
        return;
    }
    int t = blockIdx.x * 256 + threadIdx.x;        // (kt*16+nt)*64+l
    int l = t & 63;
    int k0 = (t >> 10) * 32 + ((l >> 4) * 8);
    int col = ((t >> 6) & 15) * 16 + (l & 15);
    s8 v;
    #pragma unroll
    for (int j = 0; j < 8; ++j) {
        int k = k0 + j;
        v[j] = f2bf((k < FF) ? W[(size_t)k * HH + col] : 0.f);
    }
    *(s8*)(wp + (size_t)t * 8) = v;
}

// ---- place: bucket-slab counting sort, self-allocating (no scan) ----
__global__ __launch_bounds__(256) void k_place(const int* __restrict__ row,
                                               const int* __restrict__ col,
                                               int* __restrict__ cursor,
                                               u32* __restrict__ ebuf) {
    __shared__ int lcnt[NBK], lbase[NBK];
    const int t = threadIdx.x;
    if (t < NBK) lcnt[t] = 0;
    __syncthreads();
    const int base = blockIdx.x * EB;
    for (int i = t; i < EB; i += 256)
        atomicAdd(&lcnt[col[base + i] >> 8], 1);
    __syncthreads();
    if (t < NBK) {
        int c = lcnt[t];
        if (c) lbase[t] = (t << 13) + atomicAdd(&cursor[t], c);
        lcnt[t] = 0;
    }
    __syncthreads();
    for (int i = t; i < EB; i += 256) {
        int d = col[base + i], s = row[base + i];
        int b = d >> 8;
        int lp = atomicAdd(&lcnt[b], 1);
        ebuf[lbase[b] + lp] = ((u32)s << 8) | (u32)(d & 255);
    }
}

// ---- b2: one block per bucket, ELL slice in LDS, pads = 0xFFFF ----
__global__ __launch_bounds__(256) void k_b2(const u32* __restrict__ ebuf,
                                            const int* __restrict__ cursor,
                                            int* __restrict__ cnt,
                                            u16* __restrict__ csr) {
    __shared__ u16 ell[256 * PAD];     // 32 KB
    __shared__ int h[256];
    const int t = threadIdx.x;
    const int b = blockIdx.x;
    int* elli = (int*)ell;
    for (int i = t; i < 256 * PAD / 2; i += 256) elli[i] = -1;
    h[t] = 0;
    __syncthreads();
    int cb = cursor[b];
    cb = (cb < SLOT) ? cb : SLOT;
    const int ba = b << 13;
    for (int i = t; i < cb; i += 256) {
        u32 v = ebuf[ba + i];
        int dl = v & 255;
        int s = (int)(v >> 8);
        int p = atomicAdd(&h[dl], 1);
        if (p < PAD) ell[dl * PAD + p] = (u16)s;
    }
    __syncthreads();
    const int n0 = b << 8;
    cnt[n0 + t] = h[t];
    uint4* dst = (uint4*)(csr + (size_t)n0 * PAD);
    const uint4* src = (const uint4*)ell;
    for (int i = t; i < 256 * PAD * 2 / 16; i += 256) dst[i] = src[i];
}

// ---- MFMA GEMM: h'[N,H] = rsqrt(deg+1) * (x[N,F] @ W), bf16 out ----
__global__ __launch_bounds__(256) void k_mfma(
        const float* __restrict__ x, const short* __restrict__ wp,
        const int* __restrict__ cnt, short* __restrict__ h)
{
    const int tid = threadIdx.x;
    const int l = tid & 63;
    const int w = tid >> 6;
    const int bm = blockIdx.x * 64;
    const int arow = bm + (l & 15);
    const int kl = (l >> 4) * 8;
    const s8* wb = (const s8*)wp;

    f4 acc[4][4] = {};
    for (int kt = 0; kt < NKT; ++kt) {
        const int k0 = kt * 32 + kl;
        s8 a[4];
        if (k0 < FF) {
            #pragma unroll
            for (int mi = 0; mi < 4; ++mi) {
                const float* p = x + (size_t)(arow + mi * 16) * FF + k0;
                float4 v0 = *(const float4*)p;
                float4 v1 = *(const float4*)(p + 4);
                a[mi][0] = f2bf(v0.x); a[mi][1] = f2bf(v0.y);
                a[mi][2] = f2bf(v0.z); a[mi][3] = f2bf(v0.w);
                a[mi][4] = f2bf(v1.x); a[mi][5] = f2bf(v1.y);
                a[mi][6] = f2bf(v1.z); a[mi][7] = f2bf(v1.w);
            }
        } else {
            #pragma unroll
            for (int mi = 0; mi < 4; ++mi)
                #pragma unroll
                for (int j = 0; j < 8; ++j) a[mi][j] = 0;
        }
        s8 b[4];
        #pragma unroll
        for (int ni = 0; ni < 4; ++ni)
            b[ni] = wb[(size_t)(kt * 16 + w * 4 + ni) * 64 + l];
        #pragma unroll
        for (int mi = 0; mi < 4; ++mi)
            #pragma unroll
            for (int ni = 0; ni < 4; ++ni)
                acc[mi][ni] = __builtin_amdgcn_mfma_f32_16x16x32_bf16(
                    a[mi], b[ni], acc[mi][ni], 0, 0, 0);
    }
    #pragma unroll
    for (int mi = 0; mi < 4; ++mi) {
        #pragma unroll
        for (int r = 0; r < 4; ++r) {
            const int rowg = bm + mi * 16 + (l >> 4) * 4 + r;
            const float dn = rsqrtf((float)(cnt[rowg] + 1));
            const size_t base = (size_t)rowg * HH + w * 64 + (l & 15);
            #pragma unroll
            for (int ni = 0; ni < 4; ++ni)
                h[base + ni * 16] = f2bf(dn * acc[mi][ni][r]);
        }
    }
}

// ---- gather v4: 2 nodes/wave, 16B lanes, packed f32 adds, no predicates ----
// Block 256 = 4 waves; wave w covers 4 consecutive nodes (2 per iter x 2).
// Lane: half = l>>5 owns node; li = l&31 owns channels li*8..li*8+7.
__global__ __launch_bounds__(256) void k_gather(
        const short* __restrict__ h, const int* __restrict__ cnt,
        const u16* __restrict__ csr, const int* __restrict__ batch,
        const float* __restrict__ bg, u32* __restrict__ penc)
{
    __shared__ f2 sM[256][4];      // 8 KB
    __shared__ int sB[256];
    const int t = threadIdx.x;
    const int l = t & 63;
    const int w = t >> 6;
    const int half = l >> 5, li = l & 31;
    const int ch0 = li * 8;
    const float4 b0 = *(const float4*)(bg + ch0);
    const float4 b1 = *(const float4*)(bg + ch0 + 4);

    f2 M[4];
    int runb = -1;
    const int nbase = blockIdx.x * 16 + w * 4;
    #pragma unroll
    for (int m = 0; m < 2; ++m) {
        const int n = nbase + m * 2 + half;
        const int degt = cnt[n];
        const int deg = (degt < PAD) ? degt : PAD;
        const float dn = rsqrtf((float)(degt + 1));
        const u16* cp = csr + (size_t)n * PAD;
        u32x4 sv = *(const u32x4*)(h + (size_t)n * HH + ch0);
        f2 a[4];
        a[0] = (f2){bflo(sv.x), bfhi(sv.x)};
        a[1] = (f2){bflo(sv.y), bfhi(sv.y)};
        a[2] = (f2){bflo(sv.z), bfhi(sv.z)};
        a[3] = (f2){bflo(sv.w), bfhi(sv.w)};
        int wmax = deg;
        wmax = max(wmax, __shfl_xor(wmax, 32, 64));
        u32x4 idx = *(const u32x4*)cp;
        for (int j0 = 0; j0 < wmax; j0 += 8) {
            u32x4 nxt = *(const u32x4*)(cp + j0 + 8);   // harmless overread
            #pragma unroll
            for (int k = 0; k < 8; ++k) {
                u32 ui = (idx[k >> 1] >> ((k & 1) * 16)) & 0xFFFFu;
                ui = (ui < (u32)NN) ? ui : (u32)NN;     // pad -> zero row
                u32x4 v = *(const u32x4*)(h + (size_t)ui * HH + ch0);
                a[0] += (f2){bflo(v.x), bfhi(v.x)};
                a[1] += (f2){bflo(v.y), bfhi(v.y)};
                a[2] += (f2){bflo(v.z), bfhi(v.z)};
                a[3] += (f2){bflo(v.w), bfhi(v.w)};
            }
            idx = nxt;
        }
        f2 val[4];
        val[0] = (f2){dn * a[0].x + b0.x, dn * a[0].y + b0.y};
        val[1] = (f2){dn * a[1].x + b0.z, dn * a[1].y + b0.w};
        val[2] = (f2){dn * a[2].x + b1.x, dn * a[2].y + b1.y};
        val[3] = (f2){dn * a[3].x + b1.z, dn * a[3].y + b1.w};
        #pragma unroll
        for (int q = 0; q < 4; ++q) {
            val[q].x = (val[q].x >= 0.f) ? val[q].x : NEG * val[q].x;
            val[q].y = (val[q].y >= 0.f) ? val[q].y : NEG * val[q].y;
        }
        const int b = batch[n];
        if (b != runb) {
            if (runb >= 0) {
                u32* p = penc + runb * HH + ch0;
                #pragma unroll
                for (int q = 0; q < 4; ++q) {
                    atomicMax(p + 2 * q, encf(M[q].x));
                    atomicMax(p + 2 * q + 1, encf(M[q].y));
                }
            }
            runb = b;
            #pragma unroll
            for (int q = 0; q < 4; ++q) M[q] = val[q];
        } else {
            #pragma unroll
            for (int q = 0; q < 4; ++q) {
                M[q].x = fmaxf(M[q].x, val[q].x);
                M[q].y = fmaxf(M[q].y, val[q].y);
            }
        }
    }
    #pragma unroll
    for (int q = 0; q < 4; ++q) sM[t][q] = M[q];
    sB[t] = runb;
    __syncthreads();
    // threads 0..31: merge the 8 (wave,half) segments for channel-slice li=t
    if (t < 32) {
        int curb = sB[t];
        f2 cm[4];
        #pragma unroll
        for (int q = 0; q < 4; ++q) cm[q] = sM[t][q];
        #pragma unroll
        for (int s = 1; s < 8; ++s) {
            const int idx2 = s * 32 + t;
            const int bb = sB[idx2];
            if (bb == curb) {
                #pragma unroll
                for (int q = 0; q < 4; ++q) {
                    cm[q].x = fmaxf(cm[q].x, sM[idx2][q].x);
                    cm[q].y = fmaxf(cm[q].y, sM[idx2][q].y);
                }
            } else {
                u32* p = penc + curb * HH + t * 8;
                #pragma unroll
                for (int q = 0; q < 4; ++q) {
                    atomicMax(p + 2 * q, encf(cm[q].x));
                    atomicMax(p + 2 * q + 1, encf(cm[q].y));
                }
                curb = bb;
                #pragma unroll
                for (int q = 0; q < 4; ++q) cm[q] = sM[idx2][q];
            }
        }
        u32* p = penc + curb * HH + t * 8;
        #pragma unroll
        for (int q = 0; q < 4; ++q) {
            atomicMax(p + 2 * q, encf(cm[q].x));
            atomicMax(p + 2 * q + 1, encf(cm[q].y));
        }
    }
}

// ---- decode pool + write pool out + logits, one block per graph ----
__global__ __launch_bounds__(256) void k_out(
        const u32* __restrict__ penc, const float* __restrict__ Wl,
        const float* __restrict__ bl, float* __restrict__ out)
{
    __shared__ float r0[4], r1[4];
    const int g = blockIdx.x, t = threadIdx.x;
    float v = decf(penc[g * HH + t]);
    out[GG * CC + g * HH + t] = v;
    float s0 = v * Wl[t * CC + 0];
    float s1 = v * Wl[t * CC + 1];
    #pragma unroll
    for (int off = 32; off >= 1; off >>= 1) {
        s0 += __shfl_down(s0, off, 64);
        s1 += __shfl_down(s1, off, 64);
    }
    if ((t & 63) == 0) { r0[t >> 6] = s0; r1[t >> 6] = s1; }
    __syncthreads();
    if (t == 0) {
        out[g * CC + 0] = r0[0] + r0[1] + r0[2] + r0[3] + bl[0];
        out[g * CC + 1] = r1[0] + r1[1] + r1[2] + r1[3] + bl[1];
    }
}

extern "C" void kernel_launch(void* const* d_in, const int* in_sizes, int n_in,
                              void* d_out, int out_size, void* d_ws, size_t ws_size,
                              hipStream_t stream)
{
    const float* x    = (const float*)d_in[0];
    const int*   ei   = (const int*)d_in[1];
    const int*   batch= (const int*)d_in[2];
    const float* Wg   = (const float*)d_in[3];
    const float* bg   = (const float*)d_in[4];
    const float* Wl   = (const float*)d_in[5];
    const float* bl   = (const float*)d_in[6];
    float* out = (float*)d_out;
    const int* row = ei;        // sources
    const int* col = ei + EE;   // targets

    size_t o = 0;
    char* wsb = (char*)d_ws;
    auto take = [&](size_t b) { void* p = wsb + o; o += (b + 255) & ~(size_t)255; return p; };
    short* h    = (short*)take((size_t)(NN + 1) * HH * 2);            // 26.2 MB
    int*   cursor = (int*)take((size_t)NBK * 4);                      // 256B slot
    u32*   penc = (u32*)take((size_t)GG * HH * 4);                    // adjacent
    int*   cnt  = (int*)take((size_t)NN * 4);
    u16*   csr  = (u16*)take((size_t)NN * PAD * 2);                   // 6.55 MB
    u32*   ebuf = (u32*)take((size_t)NBK * SLOT * 4);                 // 6.55 MB
    short* wp   = (short*)take((size_t)NKT * 16 * 64 * 8 * 2);        // 213 KB

    // one memset zeroes cursor AND penc (adjacent; cursor in a 256 B slot)
    hipMemsetAsync(cursor, 0, 1024 + (size_t)GG * HH * 4, stream);

    k_place<<<NBK, 256, 0, stream>>>(row, col, cursor, ebuf);
    k_b2<<<NBK, 256, 0, stream>>>(ebuf, cursor, cnt, csr);
    k_pack_w<<<NKT * 16 * 64 / 256 + 1, 256, 0, stream>>>(Wg, wp, h);
    k_mfma<<<NN / 64, 256, 0, stream>>>(x, wp, cnt, h);
    k_gather<<<NN / 16, 256, 0, stream>>>(h, cnt, csr, batch, bg, penc);
    k_out<<<GG, 256, 0, stream>>>(penc, Wl, bl, out);
}

// Round 9
// 138.843 us; speedup vs baseline: 1.2728x; 1.0511x over previous
//
#include <hip/hip_runtime.h>
#include <hip/hip_bf16.h>
#include <stdint.h>

#define NN 51200
#define FF 400
#define HH 256
#define CC 2
#define EE 819200
#define GG 128
#define NEG 0.01f
#define NKT 13          // ceil(400/32) K-tiles of 32
#define PAD 64          // padded neighbor slots per node
#define NBK 200         // dst buckets = dst>>8
#define EB  4096        // edges per block in sort passes (EE/NBK)
#define SLOT 8192       // ebuf slots per bucket (pow2)

typedef unsigned int u32;
typedef unsigned short u16;
typedef __attribute__((ext_vector_type(8))) short s8;    // 8 bf16
typedef __attribute__((ext_vector_type(4))) u32 u32x4;   // 16B vector
typedef __attribute__((ext_vector_type(2))) float f2;    // packed f32 pair
typedef __attribute__((ext_vector_type(4))) float f4;    // MFMA acc

__device__ __forceinline__ short f2bf(float f) {
    __hip_bfloat16 b = __float2bfloat16(f);
    return *reinterpret_cast<short*>(&b);
}
__device__ __forceinline__ float bflo(u32 x) { return __uint_as_float(x << 16); }
__device__ __forceinline__ float bfhi(u32 x) { return __uint_as_float(x & 0xffff0000u); }

// Order-preserving float<->uint encoding for atomicMax on floats.
__device__ __forceinline__ u32 encf(float f) {
    u32 u = __float_as_uint(f);
    return (u & 0x80000000u) ? ~u : (u | 0x80000000u);
}
__device__ __forceinline__ float decf(u32 e) {
    return (e & 0x80000000u) ? __uint_as_float(e & 0x7fffffffu)
                             : __uint_as_float(~e);
}

// ---- pack W -> fragment layout; last block zeroes dummy row h[NN] ----
__global__ void k_pack_w(const float* __restrict__ W, short* __restrict__ wp,
                         short* __restrict__ h) {
    if (blockIdx.x == gridDim.x - 1) {
        if (threadIdx.x < 128)
            ((u32*)h)[(size_t)NN * 128 + threadIdx.x] = 0;
        return;
    }
    int t = blockIdx.x * 256 + threadIdx.x;        // (kt*16+nt)*64+l
    int l = t & 63;
    int k0 = (t >> 10) * 32 + ((l >> 4) * 8);
    int col = ((t >> 6) & 15) * 16 + (l & 15);
    s8 v;
    #pragma unroll
    for (int j = 0; j < 8; ++j) {
        int k = k0 + j;
        v[j] = f2bf((k < FF) ? W[(size_t)k * HH + col] : 0.f);
    }
    *(s8*)(wp + (size_t)t * 8) = v;
}

// ---- place: bucket-slab counting sort, self-allocating (no scan) ----
__global__ __launch_bounds__(256) void k_place(const int* __restrict__ row,
                                               const int* __restrict__ col,
                                               int* __restrict__ cursor,
                                               u32* __restrict__ ebuf) {
    __shared__ int lcnt[NBK], lbase[NBK];
    const int t = threadIdx.x;
    if (t < NBK) lcnt[t] = 0;
    __syncthreads();
    const int base = blockIdx.x * EB;
    for (int i = t; i < EB; i += 256)
        atomicAdd(&lcnt[col[base + i] >> 8], 1);
    __syncthreads();
    if (t < NBK) {
        int c = lcnt[t];
        if (c) lbase[t] = (t << 13) + atomicAdd(&cursor[t], c);
        lcnt[t] = 0;
    }
    __syncthreads();
    for (int i = t; i < EB; i += 256) {
        int d = col[base + i], s = row[base + i];
        int b = d >> 8;
        int lp = atomicAdd(&lcnt[b], 1);
        ebuf[lbase[b] + lp] = ((u32)s << 8) | (u32)(d & 255);
    }
}

// ---- b2: one block per bucket, ELL slice in LDS, pads = 0xFFFF ----
__global__ __launch_bounds__(256) void k_b2(const u32* __restrict__ ebuf,
                                            const int* __restrict__ cursor,
                                            int* __restrict__ cnt,
                                            u16* __restrict__ csr) {
    __shared__ u16 ell[256 * PAD];     // 32 KB
    __shared__ int h[256];
    const int t = threadIdx.x;
    const int b = blockIdx.x;
    int* elli = (int*)ell;
    for (int i = t; i < 256 * PAD / 2; i += 256) elli[i] = -1;
    h[t] = 0;
    __syncthreads();
    int cb = cursor[b];
    cb = (cb < SLOT) ? cb : SLOT;
    const int ba = b << 13;
    for (int i = t; i < cb; i += 256) {
        u32 v = ebuf[ba + i];
        int dl = v & 255;
        int s = (int)(v >> 8);
        int p = atomicAdd(&h[dl], 1);
        if (p < PAD) ell[dl * PAD + p] = (u16)s;
    }
    __syncthreads();
    const int n0 = b << 8;
    cnt[n0 + t] = h[t];
    uint4* dst = (uint4*)(csr + (size_t)n0 * PAD);
    const uint4* src = (const uint4*)ell;
    for (int i = t; i < 256 * PAD * 2 / 16; i += 256) dst[i] = src[i];
}

// ---- MFMA GEMM with double-buffered LDS A-staging (global_load_lds) ----
// h'[N,H] = rsqrt(deg+1) * (x[N,F] @ W), bf16 out.
// Block: 256 thr = 4 waves, BM=64 rows, N=256 (wave w owns cols w*64..+64).
// A-tile: [64 rows][32 k] f32 in LDS, 16B-granule XOR swizzle (g ^= r&7).
__global__ __launch_bounds__(256) void k_mfma(
        const float* __restrict__ x, const short* __restrict__ wp,
        const int* __restrict__ cnt, short* __restrict__ h)
{
    __shared__ float As[2][2048];      // 2 x 8 KB
    const int t = threadIdx.x;
    const int l = t & 63;
    const int w = t >> 6;
    const int bm = blockIdx.x * 64;
    const s8* wb = (const s8*)wp;

    // staging geometry: granule p = inst*256 + w*64 + l -> row r=p>>3, g=p&7
    const int rA = w * 8 + (l >> 3);              // inst0 row (inst1: +32)
    const int sA = (l & 7) ^ (rA & 7);            // swizzled source slot
    const size_t base0 = (size_t)(bm + rA) * FF + sA * 4;
    const size_t base1 = (size_t)(bm + rA + 32) * FF + sA * 4;
    const size_t xmax = (size_t)NN * FF - 4;      // clamp keeps reads in-bounds

    auto stage = [&](int kt, int buf) {
        size_t i0 = base0 + (size_t)kt * 32; if (i0 > xmax) i0 = xmax;
        size_t i1 = base1 + (size_t)kt * 32; if (i1 > xmax) i1 = xmax;
        __builtin_amdgcn_global_load_lds(
            (const __attribute__((address_space(1))) void*)(x + i0),
            (__attribute__((address_space(3))) void*)(&As[buf][w * 256]),
            16, 0, 0);
        __builtin_amdgcn_global_load_lds(
            (const __attribute__((address_space(1))) void*)(x + i1),
            (__attribute__((address_space(3))) void*)(&As[buf][1024 + w * 256]),
            16, 0, 0);
    };

    f4 acc[4][4] = {};
    stage(0, 0);
    int buf = 0;
    const int s0 = (l >> 4) * 2;                  // first 16B slot of kl
    const int sx = l & 7;                         // row-derived swizzle key
    for (int kt = 0; kt < NKT; ++kt) {
        __syncthreads();                          // stage(kt) landed
        if (kt + 1 < NKT) stage(kt + 1, buf ^ 1);
        s8 a[4];
        #pragma unroll
        for (int mi = 0; mi < 4; ++mi) {
            const int r = mi * 16 + (l & 15);     // r&7 == l&7 == sx
            float4 va = *(const float4*)&As[buf][(r * 8 + (s0 ^ sx)) * 4];
            float4 vb = *(const float4*)&As[buf][(r * 8 + ((s0 + 1) ^ sx)) * 4];
            a[mi][0] = f2bf(va.x); a[mi][1] = f2bf(va.y);
            a[mi][2] = f2bf(va.z); a[mi][3] = f2bf(va.w);
            a[mi][4] = f2bf(vb.x); a[mi][5] = f2bf(vb.y);
            a[mi][6] = f2bf(vb.z); a[mi][7] = f2bf(vb.w);
        }
        s8 b[4];
        #pragma unroll
        for (int ni = 0; ni < 4; ++ni)
            b[ni] = wb[(size_t)(kt * 16 + w * 4 + ni) * 64 + l];
        #pragma unroll
        for (int mi = 0; mi < 4; ++mi)
            #pragma unroll
            for (int ni = 0; ni < 4; ++ni)
                acc[mi][ni] = __builtin_amdgcn_mfma_f32_16x16x32_bf16(
                    a[mi], b[ni], acc[mi][ni], 0, 0, 0);
        buf ^= 1;
    }
    #pragma unroll
    for (int mi = 0; mi < 4; ++mi) {
        #pragma unroll
        for (int r = 0; r < 4; ++r) {
            const int rowg = bm + mi * 16 + (l >> 4) * 4 + r;
            const float dn = rsqrtf((float)(cnt[rowg] + 1));
            const size_t base = (size_t)rowg * HH + w * 64 + (l & 15);
            #pragma unroll
            for (int ni = 0; ni < 4; ++ni)
                h[base + ni * 16] = f2bf(dn * acc[mi][ni][r]);
        }
    }
}

// ---- gather v5: 2 nodes/wave, 16B lanes, 16-deep in-flight gathers ----
// Block 256 = 4 waves; wave w covers 4 consecutive nodes (2 per iter x 2).
// Lane: half = l>>5 owns node; li = l&31 owns channels li*8..li*8+7.
__global__ __launch_bounds__(256) void k_gather(
        const short* __restrict__ h, const int* __restrict__ cnt,
        const u16* __restrict__ csr, const int* __restrict__ batch,
        const float* __restrict__ bg, u32* __restrict__ penc)
{
    __shared__ f2 sM[256][4];      // 8 KB
    __shared__ int sB[256];
    const int t = threadIdx.x;
    const int l = t & 63;
    const int w = t >> 6;
    const int half = l >> 5, li = l & 31;
    const int ch0 = li * 8;
    const float4 b0 = *(const float4*)(bg + ch0);
    const float4 b1 = *(const float4*)(bg + ch0 + 4);

    f2 M[4];
    int runb = -1;
    const int nbase = blockIdx.x * 16 + w * 4;
    #pragma unroll
    for (int m = 0; m < 2; ++m) {
        const int n = nbase + m * 2 + half;
        const int degt = cnt[n];
        const int deg = (degt < PAD) ? degt : PAD;
        const float dn = rsqrtf((float)(degt + 1));
        const u16* cp = csr + (size_t)n * PAD;
        u32x4 sv = *(const u32x4*)(h + (size_t)n * HH + ch0);
        f2 a[4];
        a[0] = (f2){bflo(sv.x), bfhi(sv.x)};
        a[1] = (f2){bflo(sv.y), bfhi(sv.y)};
        a[2] = (f2){bflo(sv.z), bfhi(sv.z)};
        a[3] = (f2){bflo(sv.w), bfhi(sv.w)};
        int wmax = deg;
        wmax = max(wmax, __shfl_xor(wmax, 32, 64));
        for (int j0 = 0; j0 < wmax; j0 += 16) {
            u32x4 ia = *(const u32x4*)(cp + j0);
            u32x4 ib = *(const u32x4*)(cp + j0 + 8);
            #pragma unroll
            for (int k = 0; k < 16; ++k) {
                const int kk = k & 7;
                u32 word = (k < 8) ? ia[kk >> 1] : ib[kk >> 1];
                u32 ui = (word >> ((kk & 1) * 16)) & 0xFFFFu;
                ui = (ui < (u32)NN) ? ui : (u32)NN;     // pad -> zero row
                u32x4 v = *(const u32x4*)(h + (size_t)ui * HH + ch0);
                a[0] += (f2){bflo(v.x), bfhi(v.x)};
                a[1] += (f2){bflo(v.y), bfhi(v.y)};
                a[2] += (f2){bflo(v.z), bfhi(v.z)};
                a[3] += (f2){bflo(v.w), bfhi(v.w)};
            }
        }
        f2 val[4];
        val[0] = (f2){dn * a[0].x + b0.x, dn * a[0].y + b0.y};
        val[1] = (f2){dn * a[1].x + b0.z, dn * a[1].y + b0.w};
        val[2] = (f2){dn * a[2].x + b1.x, dn * a[2].y + b1.y};
        val[3] = (f2){dn * a[3].x + b1.z, dn * a[3].y + b1.w};
        #pragma unroll
        for (int q = 0; q < 4; ++q) {
            val[q].x = (val[q].x >= 0.f) ? val[q].x : NEG * val[q].x;
            val[q].y = (val[q].y >= 0.f) ? val[q].y : NEG * val[q].y;
        }
        const int b = batch[n];
        if (b != runb) {
            if (runb >= 0) {
                u32* p = penc + runb * HH + ch0;
                #pragma unroll
                for (int q = 0; q < 4; ++q) {
                    atomicMax(p + 2 * q, encf(M[q].x));
                    atomicMax(p + 2 * q + 1, encf(M[q].y));
                }
            }
            runb = b;
            #pragma unroll
            for (int q = 0; q < 4; ++q) M[q] = val[q];
        } else {
            #pragma unroll
            for (int q = 0; q < 4; ++q) {
                M[q].x = fmaxf(M[q].x, val[q].x);
                M[q].y = fmaxf(M[q].y, val[q].y);
            }
        }
    }
    #pragma unroll
    for (int q = 0; q < 4; ++q) sM[t][q] = M[q];
    sB[t] = runb;
    __syncthreads();
    // threads 0..31: merge the 8 (wave,half) segments for channel-slice li=t
    if (t < 32) {
        int curb = sB[t];
        f2 cm[4];
        #pragma unroll
        for (int q = 0; q < 4; ++q) cm[q] = sM[t][q];
        #pragma unroll
        for (int s = 1; s < 8; ++s) {
            const int idx2 = s * 32 + t;
            const int bb = sB[idx2];
            if (bb == curb) {
                #pragma unroll
                for (int q = 0; q < 4; ++q) {
                    cm[q].x = fmaxf(cm[q].x, sM[idx2][q].x);
                    cm[q].y = fmaxf(cm[q].y, sM[idx2][q].y);
                }
            } else {
                u32* p = penc + curb * HH + t * 8;
                #pragma unroll
                for (int q = 0; q < 4; ++q) {
                    atomicMax(p + 2 * q, encf(cm[q].x));
                    atomicMax(p + 2 * q + 1, encf(cm[q].y));
                }
                curb = bb;
                #pragma unroll
                for (int q = 0; q < 4; ++q) cm[q] = sM[idx2][q];
            }
        }
        u32* p = penc + curb * HH + t * 8;
        #pragma unroll
        for (int q = 0; q < 4; ++q) {
            atomicMax(p + 2 * q, encf(cm[q].x));
            atomicMax(p + 2 * q + 1, encf(cm[q].y));
        }
    }
}

// ---- decode pool + write pool out + logits, one block per graph ----
__global__ __launch_bounds__(256) void k_out(
        const u32* __restrict__ penc, const float* __restrict__ Wl,
        const float* __restrict__ bl, float* __restrict__ out)
{
    __shared__ float r0[4], r1[4];
    const int g = blockIdx.x, t = threadIdx.x;
    float v = decf(penc[g * HH + t]);
    out[GG * CC + g * HH + t] = v;
    float s0 = v * Wl[t * CC + 0];
    float s1 = v * Wl[t * CC + 1];
    #pragma unroll
    for (int off = 32; off >= 1; off >>= 1) {
        s0 += __shfl_down(s0, off, 64);
        s1 += __shfl_down(s1, off, 64);
    }
    if ((t & 63) == 0) { r0[t >> 6] = s0; r1[t >> 6] = s1; }
    __syncthreads();
    if (t == 0) {
        out[g * CC + 0] = r0[0] + r0[1] + r0[2] + r0[3] + bl[0];
        out[g * CC + 1] = r1[0] + r1[1] + r1[2] + r1[3] + bl[1];
    }
}

extern "C" void kernel_launch(void* const* d_in, const int* in_sizes, int n_in,
                              void* d_out, int out_size, void* d_ws, size_t ws_size,
                              hipStream_t stream)
{
    const float* x    = (const float*)d_in[0];
    const int*   ei   = (const int*)d_in[1];
    const int*   batch= (const int*)d_in[2];
    const float* Wg   = (const float*)d_in[3];
    const float* bg   = (const float*)d_in[4];
    const float* Wl   = (const float*)d_in[5];
    const float* bl   = (const float*)d_in[6];
    float* out = (float*)d_out;
    const int* row = ei;        // sources
    const int* col = ei + EE;   // targets

    size_t o = 0;
    char* wsb = (char*)d_ws;
    auto take = [&](size_t b) { void* p = wsb + o; o += (b + 255) & ~(size_t)255; return p; };
    short* h    = (short*)take((size_t)(NN + 1) * HH * 2);            // 26.2 MB
    int*   cursor = (int*)take((size_t)NBK * 4);                      // 256B slot
    u32*   penc = (u32*)take((size_t)GG * HH * 4);                    // adjacent
    int*   cnt  = (int*)take((size_t)NN * 4);
    u16*   csr  = (u16*)take((size_t)NN * PAD * 2);                   // 6.55 MB
    u32*   ebuf = (u32*)take((size_t)NBK * SLOT * 4);                 // 6.55 MB
    short* wp   = (short*)take((size_t)NKT * 16 * 64 * 8 * 2);        // 213 KB

    // one memset zeroes cursor AND penc (adjacent; cursor in a 256 B slot)
    hipMemsetAsync(cursor, 0, 1024 + (size_t)GG * HH * 4, stream);

    k_place<<<NBK, 256, 0, stream>>>(row, col, cursor, ebuf);
    k_b2<<<NBK, 256, 0, stream>>>(ebuf, cursor, cnt, csr);
    k_pack_w<<<NKT * 16 * 64 / 256 + 1, 256, 0, stream>>>(Wg, wp, h);
    k_mfma<<<NN / 64, 256, 0, stream>>>(x, wp, cnt, h);
    k_gather<<<NN / 16, 256, 0, stream>>>(h, cnt, csr, batch, bg, penc);
    k_out<<<GG, 256, 0, stream>>>(penc, Wl, bl, out);
}